// Round 1
// baseline (347.958 us; speedup 1.0000x reference)
//
#include <hip/hip_runtime.h>
#include <hip/hip_bf16.h>
#include <stdint.h>

#define NN 4096
#define NF 128

using f32x4  = __attribute__((ext_vector_type(4))) float;
using bf16x8 = __attribute__((ext_vector_type(8))) __bf16;

__device__ __forceinline__ uint16_t f2b(float f) {
    union { float f; uint32_t u; } v; v.f = f;
    uint32_t r = v.u + 0x7FFFu + ((v.u >> 16) & 1u);
    return (uint16_t)(r >> 16);
}

__device__ __forceinline__ void gld_lds16(const void* g, void* l) {
    __builtin_amdgcn_global_load_lds(
        (const __attribute__((address_space(1))) uint32_t*)g,
        (__attribute__((address_space(3))) uint32_t*)l,
        16, 0, 0);
}

// ---------------------------------------------------------------------------
// Kernel 1: XW = X@W (one row per block), s_col = XW@a[:128], s_row = XW@a[128:]
// writes XWT (bf16, [128][4096]) for later use as a B^T GEMM operand.
// ---------------------------------------------------------------------------
__global__ void xw_kernel(const float* __restrict__ X, const float* __restrict__ W,
                          const float* __restrict__ a,
                          uint16_t* __restrict__ XWT,
                          float* __restrict__ s_col, float* __restrict__ s_row) {
    __shared__ float xs[NF];
    __shared__ float red[4];
    const int i = blockIdx.x, f = threadIdx.x;
    xs[f] = X[i * NF + f];
    __syncthreads();
    float acc = 0.f;
    #pragma unroll 8
    for (int k = 0; k < NF; ++k) acc += xs[k] * W[k * NF + f];
    XWT[(size_t)f * NN + i] = f2b(acc);
    float sc = acc * a[f];
    float sr = acc * a[NF + f];
    #pragma unroll
    for (int off = 32; off; off >>= 1) {
        sc += __shfl_down(sc, off);
        sr += __shfl_down(sr, off);
    }
    if ((f & 63) == 0) { red[f >> 6] = sc; red[2 + (f >> 6)] = sr; }
    __syncthreads();
    if (f == 0) {
        s_col[i] = red[0] + red[1];
        s_row[i] = red[2] + red[3];
    }
}

// ---------------------------------------------------------------------------
// Kernel 2: fp32 -> bf16 conversion (A matrix), 4 elems/thread
// ---------------------------------------------------------------------------
__global__ void conv_bf16_kernel(const float* __restrict__ in, uint16_t* __restrict__ out) {
    int idx = blockIdx.x * blockDim.x + threadIdx.x;
    float4 v = ((const float4*)in)[idx];
    ushort4 o;
    o.x = f2b(v.x); o.y = f2b(v.y); o.z = f2b(v.z); o.w = f2b(v.w);
    ((ushort4*)out)[idx] = o;
}

// ---------------------------------------------------------------------------
// Kernel 3: denT[j][k] = bf16(exp(leaky_relu(s_row[k] + s_col[j])))
// (den materialized TRANSPOSED so the big GEMM sees a K-contiguous B^T operand)
// ---------------------------------------------------------------------------
__global__ void denT_kernel(const float* __restrict__ s_row, const float* __restrict__ s_col,
                            uint16_t* __restrict__ denT) {
    int idx = blockIdx.x * blockDim.x + threadIdx.x;   // NN*1024 threads total
    int j = idx >> 10;
    int k = (idx & 1023) << 2;
    float sc = s_col[j];
    float4 sr = *(const float4*)(s_row + k);
    float z0 = sc + sr.x; z0 = z0 > 0.f ? z0 : 0.01f * z0;
    float z1 = sc + sr.y; z1 = z1 > 0.f ? z1 : 0.01f * z1;
    float z2 = sc + sr.z; z2 = z2 > 0.f ? z2 : 0.01f * z2;
    float z3 = sc + sr.w; z3 = z3 > 0.f ? z3 : 0.01f * z3;
    ushort4 o;
    o.x = f2b(__expf(z0)); o.y = f2b(__expf(z1));
    o.z = f2b(__expf(z2)); o.w = f2b(__expf(z3));
    *(ushort4*)(denT + (size_t)j * NN + k) = o;
}

// ---------------------------------------------------------------------------
// Shared GEMM core (m97 structure): C[i][j] = sum_k A[i,k] * Bt[j,k]
// 128x128 block tile, BK=32, 4 waves (2x2), 16x16x32 bf16 MFMA, 4x4 frags/wave.
// Staging via global_load_lds width=16.
// ---------------------------------------------------------------------------
__device__ __forceinline__ void gemm_core(
    const uint16_t* __restrict__ Ab, const uint16_t* __restrict__ Bt,
    int bm0, int bn0, int kBeg, int kEnd, int K,
    uint16_t* As, uint16_t* Bs, f32x4 acc[4][4]) {
    const int tid  = threadIdx.x;
    const int lane = tid & 63;
    const int wid  = tid >> 6;
    const int wy   = wid >> 1, wx = wid & 1;
    const int quad = lane >> 4, l16 = lane & 15;
    const int byteoff = tid * 16;           // 0..4080
    const int srow    = byteoff >> 6;       // tile row 0..63
    const int scol    = (byteoff & 63) >> 1;// element offset within the 32-elem row

    for (int k0 = kBeg; k0 < kEnd; k0 += 32) {
        __syncthreads();
        gld_lds16(Ab + (size_t)(bm0 +      srow) * K + k0 + scol, (char*)As +        byteoff);
        gld_lds16(Ab + (size_t)(bm0 + 64 + srow) * K + k0 + scol, (char*)As + 4096 + byteoff);
        gld_lds16(Bt + (size_t)(bn0 +      srow) * K + k0 + scol, (char*)Bs +        byteoff);
        gld_lds16(Bt + (size_t)(bn0 + 64 + srow) * K + k0 + scol, (char*)Bs + 4096 + byteoff);
        __syncthreads();
        bf16x8 af[4], bf[4];
        #pragma unroll
        for (int mi = 0; mi < 4; ++mi)
            af[mi] = *(const bf16x8*)((const char*)As + ((wy * 64 + mi * 16 + l16) * 64 + quad * 16));
        #pragma unroll
        for (int ni = 0; ni < 4; ++ni)
            bf[ni] = *(const bf16x8*)((const char*)Bs + ((wx * 64 + ni * 16 + l16) * 64 + quad * 16));
        #pragma unroll
        for (int mi = 0; mi < 4; ++mi)
            #pragma unroll
            for (int ni = 0; ni < 4; ++ni)
                acc[mi][ni] = __builtin_amdgcn_mfma_f32_16x16x32_bf16(af[mi], bf[ni], acc[mi][ni], 0, 0, 0);
    }
}

// ---------------------------------------------------------------------------
// Kernel 4: num = A @ den (via Ab [i][k] * denT[j][k]), fused epilogue:
//           att[i][j] = bf16( exp(lr(s_row[i]+s_col[j])) / num )
// ---------------------------------------------------------------------------
__global__ __launch_bounds__(256) void gemm_att_kernel(
    const uint16_t* __restrict__ Ab, const uint16_t* __restrict__ Bt,
    const float* __restrict__ s_row, const float* __restrict__ s_col,
    uint16_t* __restrict__ att) {
    __shared__ __align__(16) uint16_t As[128 * 32];
    __shared__ __align__(16) uint16_t Bs[128 * 32];
    const int bm0 = blockIdx.y * 128, bn0 = blockIdx.x * 128;
    f32x4 acc[4][4];
    #pragma unroll
    for (int mi = 0; mi < 4; ++mi)
        #pragma unroll
        for (int ni = 0; ni < 4; ++ni)
            acc[mi][ni] = (f32x4){0.f, 0.f, 0.f, 0.f};

    gemm_core(Ab, Bt, bm0, bn0, 0, NN, NN, As, Bs, acc);

    const int lane = threadIdx.x & 63, wid = threadIdx.x >> 6;
    const int wy = wid >> 1, wx = wid & 1;
    const int quad = lane >> 4, l16 = lane & 15;
    #pragma unroll
    for (int ni = 0; ni < 4; ++ni) {
        const int j = bn0 + wx * 64 + ni * 16 + l16;
        const float scj = s_col[j];
        #pragma unroll
        for (int mi = 0; mi < 4; ++mi) {
            #pragma unroll
            for (int r = 0; r < 4; ++r) {
                const int i = bm0 + wy * 64 + mi * 16 + quad * 4 + r;
                float z = s_row[i] + scj;
                z = z > 0.f ? z : 0.01f * z;
                const float den = __expf(z);
                const float num = acc[mi][ni][r];
                const float v = (num != 0.f) ? den / num : 0.f;
                att[(size_t)i * NN + j] = f2b(v);
            }
        }
    }
}

// ---------------------------------------------------------------------------
// Kernel 5: skinny GEMM with split-K: P[split][i][f] = sum_{k in chunk} A[i,k]*Bt[f,k]
// M=4096, N=128 (one block covers full N), K chunk = 512, 8 splits.
// ---------------------------------------------------------------------------
__global__ __launch_bounds__(256) void gemm_splitk_kernel(
    const uint16_t* __restrict__ Ab, const uint16_t* __restrict__ Bt,
    float* __restrict__ P) {
    __shared__ __align__(16) uint16_t As[128 * 32];
    __shared__ __align__(16) uint16_t Bs[128 * 32];
    const int bm0 = blockIdx.y * 128;
    const int split = blockIdx.z;
    f32x4 acc[4][4];
    #pragma unroll
    for (int mi = 0; mi < 4; ++mi)
        #pragma unroll
        for (int ni = 0; ni < 4; ++ni)
            acc[mi][ni] = (f32x4){0.f, 0.f, 0.f, 0.f};

    gemm_core(Ab, Bt, bm0, 0, split * 512, (split + 1) * 512, NN, As, Bs, acc);

    const int lane = threadIdx.x & 63, wid = threadIdx.x >> 6;
    const int wy = wid >> 1, wx = wid & 1;
    const int quad = lane >> 4, l16 = lane & 15;
    float* Pp = P + (size_t)split * (NN * NF);
    #pragma unroll
    for (int mi = 0; mi < 4; ++mi)
        #pragma unroll
        for (int ni = 0; ni < 4; ++ni)
            #pragma unroll
            for (int r = 0; r < 4; ++r) {
                const int i = bm0 + wy * 64 + mi * 16 + quad * 4 + r;
                const int j = wx * 64 + ni * 16 + l16;
                Pp[(size_t)i * NF + j] = acc[mi][ni][r];
            }
}

// ---------------------------------------------------------------------------
// Reduce kernels for split-K partials
// ---------------------------------------------------------------------------
__global__ void reduce_t_kernel(const float* __restrict__ P, uint16_t* __restrict__ M1T) {
    int idx = blockIdx.x * 256 + threadIdx.x;   // 0..524287
    float s = 0.f;
    #pragma unroll
    for (int sp = 0; sp < 8; ++sp) s += P[(size_t)sp * (NN * NF) + idx];
    int i = idx >> 7, f = idx & 127;
    M1T[(size_t)f * NN + i] = f2b(s);           // transposed bf16 for next GEMM's B^T
}

__global__ void reduce_out_kernel(const float* __restrict__ P, float* __restrict__ out) {
    int idx = blockIdx.x * 256 + threadIdx.x;
    float s = 0.f;
    #pragma unroll
    for (int sp = 0; sp < 8; ++sp) s += P[(size_t)sp * (NN * NF) + idx];
    out[idx] = s;
}

// ---------------------------------------------------------------------------
extern "C" void kernel_launch(void* const* d_in, const int* in_sizes, int n_in,
                              void* d_out, int out_size, void* d_ws, size_t ws_size,
                              hipStream_t stream) {
    (void)in_sizes; (void)n_in; (void)out_size; (void)ws_size;
    const float* X = (const float*)d_in[0];
    const float* A = (const float*)d_in[1];
    const float* W = (const float*)d_in[2];
    const float* a = (const float*)d_in[3];
    float* H = (float*)d_out;

    char* ws = (char*)d_ws;
    uint16_t* Ab   = (uint16_t*)(ws);                          // 32 MB
    uint16_t* denT = (uint16_t*)(ws + ((size_t)32 << 20));     // 32 MB
    uint16_t* att  = (uint16_t*)(ws + ((size_t)64 << 20));     // 32 MB
    uint16_t* XWT  = (uint16_t*)(ws + ((size_t)96 << 20));     // 1 MB
    uint16_t* M1T  = (uint16_t*)(ws + ((size_t)97 << 20));     // 1 MB
    float*    s_col= (float*)   (ws + ((size_t)98 << 20));     // 16 KB
    float*    s_row= (float*)   (ws + ((size_t)98 << 20) + 16384); // 16 KB
    float*    P    = (float*)   (ws + ((size_t)99 << 20));     // 16 MB

    // 1. XW + scores (+ XWT bf16)
    xw_kernel<<<NN, NF, 0, stream>>>(X, W, a, XWT, s_col, s_row);
    // 2. A -> bf16
    conv_bf16_kernel<<<(NN * NN / 4) / 256, 256, 0, stream>>>(A, Ab);
    // 3. denT bf16
    denT_kernel<<<(NN * 1024) / 256, 256, 0, stream>>>(s_row, s_col, denT);
    // 4. num = A@den with fused att epilogue
    gemm_att_kernel<<<dim3(32, 32), 256, 0, stream>>>(Ab, denT, s_row, s_col, att);
    // 5. M1 = att @ XW (split-K partials)
    gemm_splitk_kernel<<<dim3(1, 32, 8), 256, 0, stream>>>(att, XWT, P);
    // 6. reduce + transpose -> M1T bf16
    reduce_t_kernel<<<(NN * NF) / 256, 256, 0, stream>>>(P, M1T);
    // 7. H = A @ M1 (split-K partials)
    gemm_splitk_kernel<<<dim3(1, 32, 8), 256, 0, stream>>>(Ab, M1T, P);
    // 8. reduce -> output
    reduce_out_kernel<<<(NN * NF) / 256, 256, 0, stream>>>(P, H);
}